// Round 2
// baseline (1018.557 us; speedup 1.0000x reference)
//
#include <hip/hip_runtime.h>

typedef unsigned short u16;
typedef __attribute__((ext_vector_type(8))) short short8;
typedef __attribute__((ext_vector_type(4))) float f32x4;

__device__ __forceinline__ float bf2f(u16 u){
  unsigned v = ((unsigned)u) << 16;
  return __builtin_bit_cast(float, v);
}
__device__ __forceinline__ u16 f2bf(float f){
  unsigned u = __builtin_bit_cast(unsigned, f);
  u += 0x7fff + ((u >> 16) & 1);   // RNE
  return (u16)(u >> 16);
}
__device__ __forceinline__ void async16(const void* g, void* l){
  __builtin_amdgcn_global_load_lds((const __attribute__((address_space(1))) void*)g,
                                   (__attribute__((address_space(3))) void*)l, 16, 0, 0);
}

// ---------------- ada = c @ ada_w + ada_b   [8, 6144] ----------------
__global__ __launch_bounds__(256) void ada_kernel(
    const float* __restrict__ c, const float* __restrict__ aw,
    const float* __restrict__ ab, float* __restrict__ ada){
  int idx = blockIdx.x*256 + threadIdx.x;       // 49152 threads
  int b = idx / 6144, n = idx % 6144;
  float acc = ab[n];
  const float* cr = c + b*1024;
  for (int k = 0; k < 1024; ++k)
    acc += cr[k] * aw[(size_t)k*6144 + n];
  ada[idx] = acc;
}

// ---------------- transpose + cast f32[K][N] -> bf16[N][K] ----------------
__global__ __launch_bounds__(256) void transpose_cast(
    const float* __restrict__ src, u16* __restrict__ dst, int K, int N){
  __shared__ float t[64][65];
  int n0 = blockIdx.x*64, k0 = blockIdx.y*64;
  int tid = threadIdx.x;
  int cc = tid & 63, r4 = tid >> 6;
#pragma unroll 4
  for (int it = 0; it < 16; ++it){
    int r = it*4 + r4;
    t[r][cc] = src[(size_t)(k0 + r)*N + n0 + cc];
  }
  __syncthreads();
#pragma unroll 4
  for (int it = 0; it < 16; ++it){
    int r = it*4 + r4;                           // dst row = n index
    dst[(size_t)(n0 + r)*K + k0 + cc] = f2bf(t[cc][r]);
  }
}

// ---------------- LayerNorm + adaLN modulate -> bf16 ----------------
__global__ __launch_bounds__(256) void ln_mod(
    const float* __restrict__ x, u16* __restrict__ out,
    const float* __restrict__ w, const float* __restrict__ ada,
    int shift_off, int scale_off){
  int t = blockIdx.x, tid = threadIdx.x;
  const float* xr = x + (size_t)t*1024;
  float v[4]; float s = 0.f, ss = 0.f;
#pragma unroll
  for (int i = 0; i < 4; ++i){ v[i] = xr[tid + i*256]; s += v[i]; ss += v[i]*v[i]; }
  for (int d = 1; d < 64; d <<= 1){ s += __shfl_xor(s, d); ss += __shfl_xor(ss, d); }
  __shared__ float red[8];
  int wv = tid >> 6;
  if ((tid & 63) == 0){ red[wv] = s; red[4+wv] = ss; }
  __syncthreads();
  s = red[0]+red[1]+red[2]+red[3];
  ss = red[4]+red[5]+red[6]+red[7];
  float mu = s * (1.f/1024.f);
  float var = ss * (1.f/1024.f) - mu*mu;
  float rs = rsqrtf(var + 1e-5f);
  int b = t >> 10;
  const float* sh = ada + b*6144 + shift_off;
  const float* sc = ada + b*6144 + scale_off;
#pragma unroll
  for (int i = 0; i < 4; ++i){
    int cidx = tid + i*256;
    float hh = (v[i]-mu)*rs*w[cidx]*(1.f + sc[cidx]) + sh[cidx];
    out[(size_t)t*1024 + cidx] = f2bf(hh);
  }
}

// ---------------- GEMM: A[M][K] bf16 @ Bt[N][K]^T, 128x128 tile ----------------
// EPI: 0 = store bf16 ; 1 = xmid = x + g_msa*acc -> f32
//      2 = gelu(acc + b1) -> bf16 ; 3 = out = xmid + g_mlp*(acc + b2) -> f32
template<int EPI>
__global__ __launch_bounds__(256) void gemm_bt(
    const u16* __restrict__ A, const u16* __restrict__ Bt,
    void* __restrict__ Cout, int M, int N, int K, int m_off,
    const float* __restrict__ e0, const float* __restrict__ e1,
    const float* __restrict__ e2){
  __shared__ u16 As[128*32];
  __shared__ u16 Bs[128*32];
  const int tid = threadIdx.x;
  const int n0 = blockIdx.x*128, m0 = blockIdx.y*128;
  const int w = tid >> 6, lane = tid & 63, quad = lane >> 4, ln = lane & 15;
  const int wm = (w >> 1)*64, wn = (w & 1)*64;
  f32x4 acc[4][4] = {};
  const u16* ga = A  + (size_t)(m0 + (tid>>2))*K + (tid&3)*8;
  const u16* gb = Bt + (size_t)(n0 + (tid>>2))*K + (tid&3)*8;
  u16* lA = As + (tid & 192)*8;    // wave-uniform base; HW adds lane*16B
  u16* lB = Bs + (tid & 192)*8;
  const size_t rstep = (size_t)64*K;
  for (int k0 = 0; k0 < K; k0 += 32){
    async16(ga,         lA);
    async16(ga + rstep, lA + 2048);
    async16(gb,         lB);
    async16(gb + rstep, lB + 2048);
    ga += 32; gb += 32;
    __syncthreads();
    short8 af[4], bfr[4];
#pragma unroll
    for (int i = 0; i < 4; ++i){
      af[i]  = *(const short8*)(As + (wm + i*16 + ln)*32 + quad*8);
      bfr[i] = *(const short8*)(Bs + (wn + i*16 + ln)*32 + quad*8);
    }
#pragma unroll
    for (int i = 0; i < 4; ++i)
#pragma unroll
      for (int j = 0; j < 4; ++j)
        acc[i][j] = __builtin_amdgcn_mfma_f32_16x16x32_bf16(af[i], bfr[j], acc[i][j], 0, 0, 0);
    __syncthreads();
  }
  const int mB = m0 + wm + quad*4;
  const int nB = n0 + wn + ln;
#pragma unroll
  for (int i = 0; i < 4; ++i){
#pragma unroll
    for (int r = 0; r < 4; ++r){
      const int m = mB + i*16 + r;
#pragma unroll
      for (int j = 0; j < 4; ++j){
        const int n = nB + j*16;
        float v = acc[i][j][r];
        if (EPI == 0){
          ((u16*)Cout)[(size_t)m*N + n] = f2bf(v);
        } else if (EPI == 1){
          const int b = (m + m_off) >> 10;
          float g = e1[b*6144 + 2048 + n];
          ((float*)Cout)[(size_t)m*N + n] = e0[(size_t)m*N + n] + g*v;
        } else if (EPI == 2){
          float xx = v + e0[n];
          float th = tanhf(0.7978845608f*(xx + 0.044715f*xx*xx*xx));
          ((u16*)Cout)[(size_t)m*N + n] = f2bf(0.5f*xx*(1.0f + th));
        } else {
          const int b = (m + m_off) >> 10;
          float g = e1[b*6144 + 5120 + n];
          ((float*)Cout)[(size_t)m*N + n] = e2[(size_t)m*N + n] + g*(v + e0[n]);
        }
      }
    }
  }
}

// ---------------- RoPE + repack q,k -> [B,H,L,D]; v -> [B,H,D,L] ----------------
__global__ __launch_bounds__(256) void rope_pack(
    const u16* __restrict__ qkv, const float* __restrict__ cosT,
    const float* __restrict__ sinT, u16* __restrict__ qp,
    u16* __restrict__ kp, u16* __restrict__ vt){
  int blk = blockIdx.x;                       // B*H*(L/64) = 2048
  int lt = blk & 15, h = (blk >> 4) & 15, b = blk >> 8;
  int l0 = lt*64;
  __shared__ u16 vl[64][68];
  int tid = threadIdx.x;
#pragma unroll 4
  for (int it = 0; it < 16; ++it){
    int idx = it*256 + tid;
    int r = idx >> 6, d = idx & 63;
    int t = b*1024 + l0 + r;
    int pos = l0 + r;                          // positions[t] == l (tiled arange)
    const u16* row = qkv + (size_t)t*3072 + h*64;
    float qv = bf2f(row[d]), kv = bf2f(row[1024+d]);
    float qo, ko;
    if (d < 32){
      float cs = cosT[pos*32 + d], sn = sinT[pos*32 + d];
      qo = qv*cs - bf2f(row[d+32])*sn;
      ko = kv*cs - bf2f(row[1024+d+32])*sn;
    } else {
      int dd = d - 32;
      float cs = cosT[pos*32 + dd], sn = sinT[pos*32 + dd];
      qo = qv*cs + bf2f(row[d-32])*sn;
      ko = kv*cs + bf2f(row[1024+d-32])*sn;
    }
    size_t base = ((size_t)(b*16 + h)*1024 + l0 + r)*64 + d;
    qp[base] = f2bf(qo);
    kp[base] = f2bf(ko);
    vl[d][r] = row[2048 + d];
  }
  __syncthreads();
#pragma unroll 4
  for (int it = 0; it < 16; ++it){
    int idx = it*256 + tid;
    int d = idx >> 6, cc = idx & 63;
    vt[((size_t)(b*16 + h)*64 + d)*1024 + l0 + cc] = vl[d][cc];
  }
}

// ---------------- flash attention: wave = 16 q-rows, K-tiles of 32 ----------------
__global__ __launch_bounds__(256) void attn_kernel(
    const u16* __restrict__ qp, const u16* __restrict__ kp,
    const u16* __restrict__ vtp, u16* __restrict__ ao){
  __shared__ u16 plds[4][16*48];
  int tid = threadIdx.x, w = tid >> 6, lane = tid & 63;
  int quad = lane >> 4, ln = lane & 15;
  int gw = blockIdx.x*4 + w;                   // 8192 waves
  int bh = gw >> 6, qt = gw & 63;
  int h = bh & 15, b = bh >> 4;
  const u16* Q  = qp  + ((size_t)bh*1024 + qt*16)*64;
  const u16* Kp = kp  + (size_t)bh*1024*64;
  const u16* Vt = vtp + (size_t)bh*64*1024;
  short8 qa0 = *(const short8*)(Q + ln*64 + quad*8);       // A[m=ln][k=quad*8+j]
  short8 qa1 = *(const short8*)(Q + ln*64 + 32 + quad*8);
  f32x4 o[4] = {};
  float mr[4], lr[4];
#pragma unroll
  for (int r = 0; r < 4; ++r){ mr[r] = -1e30f; lr[r] = 0.f; }
  u16* P = plds[w];
  for (int kt = 0; kt < 32; ++kt){
    const u16* Kb = Kp + (size_t)kt*32*64;
    short8 k00 = *(const short8*)(Kb + ln*64 + quad*8);          // keys 0-15, d 0-31
    short8 k01 = *(const short8*)(Kb + ln*64 + 32 + quad*8);     // keys 0-15, d 32-63
    short8 k10 = *(const short8*)(Kb + (16+ln)*64 + quad*8);     // keys 16-31
    short8 k11 = *(const short8*)(Kb + (16+ln)*64 + 32 + quad*8);
    f32x4 s0 = {}, s1 = {};
    s0 = __builtin_amdgcn_mfma_f32_16x16x32_bf16(qa0, k00, s0, 0,0,0);
    s0 = __builtin_amdgcn_mfma_f32_16x16x32_bf16(qa1, k01, s0, 0,0,0);
    s1 = __builtin_amdgcn_mfma_f32_16x16x32_bf16(qa0, k10, s1, 0,0,0);
    s1 = __builtin_amdgcn_mfma_f32_16x16x32_bf16(qa1, k11, s1, 0,0,0);
    float mx[4], al[4], p0[4], p1[4];
#pragma unroll
    for (int r = 0; r < 4; ++r){
      s0[r] *= 0.125f; s1[r] *= 0.125f;
      mx[r] = fmaxf(s0[r], s1[r]);
    }
#pragma unroll
    for (int d = 1; d < 16; d <<= 1)
#pragma unroll
      for (int r = 0; r < 4; ++r) mx[r] = fmaxf(mx[r], __shfl_xor(mx[r], d));
    float rsum[4];
#pragma unroll
    for (int r = 0; r < 4; ++r){
      float mn = fmaxf(mr[r], mx[r]);
      al[r] = __expf(mr[r] - mn);
      mr[r] = mn;
      p0[r] = __expf(s0[r] - mn);
      p1[r] = __expf(s1[r] - mn);
      rsum[r] = p0[r] + p1[r];
    }
#pragma unroll
    for (int d = 1; d < 16; d <<= 1)
#pragma unroll
      for (int r = 0; r < 4; ++r) rsum[r] += __shfl_xor(rsum[r], d);
#pragma unroll
    for (int r = 0; r < 4; ++r) lr[r] = lr[r]*al[r] + rsum[r];
#pragma unroll
    for (int n = 0; n < 4; ++n)
#pragma unroll
      for (int r = 0; r < 4; ++r) o[n][r] *= al[r];
    // P: C-layout -> LDS -> A-layout (intra-wave; DS pipe is in-order per wave)
#pragma unroll
    for (int r = 0; r < 4; ++r){
      P[(quad*4 + r)*48 + ln]      = f2bf(p0[r]);
      P[(quad*4 + r)*48 + 16 + ln] = f2bf(p1[r]);
    }
    short8 pa = *(const short8*)(P + ln*48 + quad*8);
#pragma unroll
    for (int n = 0; n < 4; ++n){
      short8 vb = *(const short8*)(Vt + (size_t)(n*16 + ln)*1024 + kt*32 + quad*8);
      o[n] = __builtin_amdgcn_mfma_f32_16x16x32_bf16(pa, vb, o[n], 0,0,0);
    }
  }
#pragma unroll
  for (int n = 0; n < 4; ++n)
#pragma unroll
    for (int r = 0; r < 4; ++r){
      float v = o[n][r] / lr[r];
      int t = b*1024 + qt*16 + quad*4 + r;
      ao[(size_t)t*1024 + h*64 + n*16 + ln] = f2bf(v);
    }
}

// ---------------- launch ----------------
// Workspace arena (120.25 MiB total; lifetimes do not overlap within a region):
//   [0          ) ada      0.1875 MB
//   [0.25  MB   ) wqkvt    6 MB   [3072][1024] bf16
//   [6.25  MB   ) wot      2 MB
//   [8.25  MB   ) w1t      8 MB   [4096][1024]
//   [16.25 MB   ) w2t      8 MB   [1024][4096]
//   [24.25 MB   ) region A 16 MB : h -> qp -> h2
//   [40.25 MB   ) region B 48 MB : qkv -> { attnb(16) | xmid(32 f32) }
//   [88.25 MB   ) region C 32 MB : kp+vt -> hid (MLP chunked over M, 2x4096 rows)
extern "C" void kernel_launch(void* const* d_in, const int* in_sizes, int n_in,
                              void* d_out, int out_size, void* d_ws, size_t ws_size,
                              hipStream_t stream){
  const float* x    = (const float*)d_in[0];
  const float* cosT = (const float*)d_in[3];
  const float* sinT = (const float*)d_in[4];
  const float* c    = (const float*)d_in[6];
  const float* ln1w = (const float*)d_in[7];
  const float* Wq   = (const float*)d_in[8];
  const float* Wk   = (const float*)d_in[9];
  const float* Wv   = (const float*)d_in[10];
  const float* Wo   = (const float*)d_in[11];
  const float* ln2w = (const float*)d_in[12];
  const float* W1   = (const float*)d_in[13];
  const float* b1   = (const float*)d_in[14];
  const float* W2   = (const float*)d_in[15];
  const float* b2   = (const float*)d_in[16];
  const float* adaW = (const float*)d_in[17];
  const float* adaB = (const float*)d_in[18];

  char* ws = (char*)d_ws;
  float* ada  = (float*)(ws);
  u16* wqkvt  = (u16*)  (ws + 262144);
  u16* wot    = (u16*)  (ws + 6553600);
  u16* w1t    = (u16*)  (ws + 8650752);
  u16* w2t    = (u16*)  (ws + 17039360);
  // region A (16 MB)
  u16* h      = (u16*)  (ws + 25427968);
  u16* qp     = (u16*)  (ws + 25427968);
  u16* h2     = (u16*)  (ws + 25427968);
  // region B (48 MB)
  u16* qkv    = (u16*)  (ws + 42205184);   // [8192][3072]
  u16* attnb  = (u16*)  (ws + 42205184);   // [8192][1024] (first 16 MB)
  float* xmid = (float*)(ws + 58982400);   // [8192][1024] f32 (next 32 MB)
  // region C (32 MB)
  u16* kp     = (u16*)  (ws + 92536832);   // [B,H,L,D]
  u16* vt     = (u16*)  (ws + 109314048);  // [B,H,D,L]
  u16* hid    = (u16*)  (ws + 92536832);   // [4096][4096] per M-chunk
  float* out  = (float*)d_out;

  ada_kernel<<<192, 256, 0, stream>>>(c, adaW, adaB, ada);
  transpose_cast<<<dim3(16,16), 256, 0, stream>>>(Wq, wqkvt,             1024, 1024);
  transpose_cast<<<dim3(16,16), 256, 0, stream>>>(Wk, wqkvt + 1024*1024, 1024, 1024);
  transpose_cast<<<dim3(16,16), 256, 0, stream>>>(Wv, wqkvt + 2048*1024, 1024, 1024);
  transpose_cast<<<dim3(16,16), 256, 0, stream>>>(Wo, wot,               1024, 1024);
  transpose_cast<<<dim3(64,16), 256, 0, stream>>>(W1, w1t,               1024, 4096);
  transpose_cast<<<dim3(16,64), 256, 0, stream>>>(W2, w2t,               4096, 1024);
  ln_mod<<<8192, 256, 0, stream>>>(x, h, ln1w, ada, 0, 1024);
  gemm_bt<0><<<dim3(24,64), 256, 0, stream>>>(h, wqkvt, qkv, 8192, 3072, 1024, 0,
                                              nullptr, nullptr, nullptr);
  rope_pack<<<2048, 256, 0, stream>>>(qkv, cosT, sinT, qp, kp, vt);
  attn_kernel<<<2048, 256, 0, stream>>>(qp, kp, vt, attnb);
  gemm_bt<1><<<dim3(8,64), 256, 0, stream>>>(attnb, wot, xmid, 8192, 1024, 1024, 0,
                                             x, ada, nullptr);
  ln_mod<<<8192, 256, 0, stream>>>(xmid, h2, ln2w, ada, 3072, 4096);
  for (int cch = 0; cch < 2; ++cch){
    const size_t mo = (size_t)cch*4096;
    gemm_bt<2><<<dim3(32,32), 256, 0, stream>>>(h2 + mo*1024, w1t, hid,
                                                4096, 4096, 1024, (int)mo,
                                                b1, nullptr, nullptr);
    gemm_bt<3><<<dim3(8,32), 256, 0, stream>>>(hid, w2t, out + mo*1024,
                                               4096, 1024, 4096, (int)mo,
                                               b2, ada, xmid + mo*1024);
  }
}

// Round 3
// 917.298 us; speedup vs baseline: 1.1104x; 1.1104x over previous
//
#include <hip/hip_runtime.h>

typedef unsigned short u16;
typedef __attribute__((ext_vector_type(8))) short short8;
typedef __attribute__((ext_vector_type(4))) float f32x4;
typedef __attribute__((ext_vector_type(4))) unsigned uint4v;

__device__ __forceinline__ float bf2f(u16 u){
  unsigned v = ((unsigned)u) << 16;
  return __builtin_bit_cast(float, v);
}
__device__ __forceinline__ u16 f2bf(float f){
  unsigned u = __builtin_bit_cast(unsigned, f);
  u += 0x7fff + ((u >> 16) & 1);   // RNE
  return (u16)(u >> 16);
}
__device__ __forceinline__ unsigned packbf(float lo, float hi){
  return ((unsigned)f2bf(hi) << 16) | (unsigned)f2bf(lo);
}
__device__ __forceinline__ void async16(const void* g, void* l){
  __builtin_amdgcn_global_load_lds((const __attribute__((address_space(1))) void*)g,
                                   (__attribute__((address_space(3))) void*)l, 16, 0, 0);
}

// ---------------- ada = c @ ada_w + ada_b   [8, 6144] ----------------
__global__ __launch_bounds__(256) void ada_kernel(
    const float* __restrict__ c, const float* __restrict__ aw,
    const float* __restrict__ ab, float* __restrict__ ada){
  int idx = blockIdx.x*256 + threadIdx.x;
  int b = idx / 6144, n = idx % 6144;
  float acc = ab[n];
  const float* cr = c + b*1024;
  for (int k = 0; k < 1024; ++k)
    acc += cr[k] * aw[(size_t)k*6144 + n];
  ada[idx] = acc;
}

// ---------------- transpose + cast f32[K][N] -> bf16[N][K] ----------------
__global__ __launch_bounds__(256) void transpose_cast(
    const float* __restrict__ src, u16* __restrict__ dst, int K, int N){
  __shared__ float t[64][65];
  int n0 = blockIdx.x*64, k0 = blockIdx.y*64;
  int tid = threadIdx.x;
  int cc = tid & 63, r4 = tid >> 6;
#pragma unroll 4
  for (int it = 0; it < 16; ++it){
    int r = it*4 + r4;
    t[r][cc] = src[(size_t)(k0 + r)*N + n0 + cc];
  }
  __syncthreads();
#pragma unroll 4
  for (int it = 0; it < 16; ++it){
    int r = it*4 + r4;
    dst[(size_t)(n0 + r)*K + k0 + cc] = f2bf(t[cc][r]);
  }
}

// ---------------- LayerNorm + adaLN modulate -> bf16 ----------------
__global__ __launch_bounds__(256) void ln_mod(
    const float* __restrict__ x, u16* __restrict__ out,
    const float* __restrict__ w, const float* __restrict__ ada,
    int shift_off, int scale_off){
  int t = blockIdx.x, tid = threadIdx.x;
  const float* xr = x + (size_t)t*1024;
  float v[4]; float s = 0.f, ss = 0.f;
#pragma unroll
  for (int i = 0; i < 4; ++i){ v[i] = xr[tid + i*256]; s += v[i]; ss += v[i]*v[i]; }
  for (int d = 1; d < 64; d <<= 1){ s += __shfl_xor(s, d); ss += __shfl_xor(ss, d); }
  __shared__ float red[8];
  int wv = tid >> 6;
  if ((tid & 63) == 0){ red[wv] = s; red[4+wv] = ss; }
  __syncthreads();
  s = red[0]+red[1]+red[2]+red[3];
  ss = red[4]+red[5]+red[6]+red[7];
  float mu = s * (1.f/1024.f);
  float var = ss * (1.f/1024.f) - mu*mu;
  float rs = rsqrtf(var + 1e-5f);
  int b = t >> 10;
  const float* sh = ada + b*6144 + shift_off;
  const float* sc = ada + b*6144 + scale_off;
#pragma unroll
  for (int i = 0; i < 4; ++i){
    int cidx = tid + i*256;
    float hh = (v[i]-mu)*rs*w[cidx]*(1.f + sc[cidx]) + sh[cidx];
    out[(size_t)t*1024 + cidx] = f2bf(hh);
  }
}

// ---------------- GEMM: A[M][K] bf16 @ Bt[N][K]^T, 128x128 tile ----------------
template<int EPI>
__global__ __launch_bounds__(256) void gemm_bt(
    const u16* __restrict__ A, const u16* __restrict__ Bt,
    void* __restrict__ Cout, int M, int N, int K, int m_off,
    const float* __restrict__ e0, const float* __restrict__ e1,
    const float* __restrict__ e2){
  __shared__ u16 As[128*32];
  __shared__ u16 Bs[128*32];
  const int tid = threadIdx.x;
  const int n0 = blockIdx.x*128, m0 = blockIdx.y*128;
  const int w = tid >> 6, lane = tid & 63, quad = lane >> 4, ln = lane & 15;
  const int wm = (w >> 1)*64, wn = (w & 1)*64;
  f32x4 acc[4][4] = {};
  const u16* ga = A  + (size_t)(m0 + (tid>>2))*K + (tid&3)*8;
  const u16* gb = Bt + (size_t)(n0 + (tid>>2))*K + (tid&3)*8;
  u16* lA = As + (tid & 192)*8;
  u16* lB = Bs + (tid & 192)*8;
  const size_t rstep = (size_t)64*K;
  for (int k0 = 0; k0 < K; k0 += 32){
    async16(ga,         lA);
    async16(ga + rstep, lA + 2048);
    async16(gb,         lB);
    async16(gb + rstep, lB + 2048);
    ga += 32; gb += 32;
    __syncthreads();
    short8 af[4], bfr[4];
#pragma unroll
    for (int i = 0; i < 4; ++i){
      af[i]  = *(const short8*)(As + (wm + i*16 + ln)*32 + quad*8);
      bfr[i] = *(const short8*)(Bs + (wn + i*16 + ln)*32 + quad*8);
    }
#pragma unroll
    for (int i = 0; i < 4; ++i)
#pragma unroll
      for (int j = 0; j < 4; ++j)
        acc[i][j] = __builtin_amdgcn_mfma_f32_16x16x32_bf16(af[i], bfr[j], acc[i][j], 0, 0, 0);
    __syncthreads();
  }
  const int mB = m0 + wm + quad*4;
  const int nB = n0 + wn + ln;
#pragma unroll
  for (int i = 0; i < 4; ++i){
#pragma unroll
    for (int r = 0; r < 4; ++r){
      const int m = mB + i*16 + r;
#pragma unroll
      for (int j = 0; j < 4; ++j){
        const int n = nB + j*16;
        float v = acc[i][j][r];
        if (EPI == 0){
          ((u16*)Cout)[(size_t)m*N + n] = f2bf(v);
        } else if (EPI == 1){
          const int b = (m + m_off) >> 10;
          float g = e1[b*6144 + 2048 + n];
          ((float*)Cout)[(size_t)m*N + n] = e0[(size_t)m*N + n] + g*v;
        } else if (EPI == 2){
          float xx = v + e0[n];
          float th = tanhf(0.7978845608f*(xx + 0.044715f*xx*xx*xx));
          ((u16*)Cout)[(size_t)m*N + n] = f2bf(0.5f*xx*(1.0f + th));
        } else {
          const int b = (m + m_off) >> 10;
          float g = e1[b*6144 + 5120 + n];
          ((float*)Cout)[(size_t)m*N + n] = e2[(size_t)m*N + n] + g*(v + e0[n]);
        }
      }
    }
  }
}

// ---------------- RoPE + repack; q pre-scaled by 1/sqrt(D)=0.125 ----------------
__global__ __launch_bounds__(256) void rope_pack(
    const u16* __restrict__ qkv, const float* __restrict__ cosT,
    const float* __restrict__ sinT, u16* __restrict__ qp,
    u16* __restrict__ kp, u16* __restrict__ vt){
  int blk = blockIdx.x;                       // B*H*(L/64) = 2048
  int lt = blk & 15, h = (blk >> 4) & 15, b = blk >> 8;
  int l0 = lt*64;
  __shared__ u16 vl[64][68];
  int tid = threadIdx.x;
#pragma unroll 4
  for (int it = 0; it < 16; ++it){
    int idx = it*256 + tid;
    int r = idx >> 6, d = idx & 63;
    int t = b*1024 + l0 + r;
    int pos = l0 + r;
    const u16* row = qkv + (size_t)t*3072 + h*64;
    float qv = bf2f(row[d]), kv = bf2f(row[1024+d]);
    float qo, ko;
    if (d < 32){
      float cs = cosT[pos*32 + d], sn = sinT[pos*32 + d];
      qo = qv*cs - bf2f(row[d+32])*sn;
      ko = kv*cs - bf2f(row[1024+d+32])*sn;
    } else {
      int dd = d - 32;
      float cs = cosT[pos*32 + dd], sn = sinT[pos*32 + dd];
      qo = qv*cs + bf2f(row[d-32])*sn;
      ko = kv*cs + bf2f(row[1024+d-32])*sn;
    }
    size_t base = ((size_t)(b*16 + h)*1024 + l0 + r)*64 + d;
    qp[base] = f2bf(qo*0.125f);
    kp[base] = f2bf(ko);
    vl[d][r] = row[2048 + d];
  }
  __syncthreads();
#pragma unroll 4
  for (int it = 0; it < 16; ++it){
    int idx = it*256 + tid;
    int d = idx >> 6, cc = idx & 63;
    vt[((size_t)(b*16 + h)*64 + d)*1024 + l0 + cc] = vl[d][cc];
  }
}

// ---------------- flash attention v2: S^T layout, 64 keys/iter ----------------
// S^T = K·Q^T  (A-frag = K rows, B-frag = Q rows) -> C: row=key(quad*4+r), col=qrow(ln)
// per-lane scalar m/l (qrow = ln); in-lane reductions + 2 shuffle stages
// PV: O^T = V^T·P^T (A-frag = Vt rows d); P^T remap via 16 one-stage shuffles
__device__ __forceinline__ void attn_tile(
    const u16* __restrict__ Kp, const u16* __restrict__ Vt,
    int kt, int ktn,
    short8 (&kc)[4][2], short8 (&kn)[4][2],
    const short8& qf0, const short8& qf1,
    f32x4 (&o)[4], float& m, float& l, int quad, int ln){
  f32x4 zz = {0.f, 0.f, 0.f, 0.f};
  f32x4 st[4];
#pragma unroll
  for (int c = 0; c < 4; ++c){
    st[c] = __builtin_amdgcn_mfma_f32_16x16x32_bf16(kc[c][0], qf0, zz, 0,0,0);
    st[c] = __builtin_amdgcn_mfma_f32_16x16x32_bf16(kc[c][1], qf1, st[c], 0,0,0);
  }
  // prefetch next K tile (latency hidden under softmax+PV)
#pragma unroll
  for (int c = 0; c < 4; ++c){
    const u16* kr = Kp + ((size_t)ktn*64 + c*16 + ln)*64 + quad*8;
    kn[c][0] = *(const short8*)kr;
    kn[c][1] = *(const short8*)(kr + 32);
  }
  // V loads for current tile (needed after softmax ~300cyc later)
  short8 va[4][2];
#pragma unroll
  for (int dc = 0; dc < 4; ++dc)
#pragma unroll
    for (int kh = 0; kh < 2; ++kh)
      va[dc][kh] = *(const short8*)(Vt + (size_t)(dc*16+ln)*1024 + kt*64 + kh*32 + quad*8);
  // ---- softmax (per-lane: qrow = ln) ----
  float mx = st[0][0];
#pragma unroll
  for (int c = 0; c < 4; ++c)
#pragma unroll
    for (int r = 0; r < 4; ++r) mx = fmaxf(mx, st[c][r]);
  mx = fmaxf(mx, __shfl_xor(mx, 16));
  mx = fmaxf(mx, __shfl_xor(mx, 32));
  float mn = fmaxf(m, mx);
  float alpha = __expf(m - mn);
  m = mn;
  float p[4][4];
#pragma unroll
  for (int c = 0; c < 4; ++c)
#pragma unroll
    for (int r = 0; r < 4; ++r) p[c][r] = __expf(st[c][r] - mn);
  float sum = ((p[0][0]+p[0][1]) + (p[0][2]+p[0][3])) + ((p[1][0]+p[1][1]) + (p[1][2]+p[1][3]))
            + ((p[2][0]+p[2][1]) + (p[2][2]+p[2][3])) + ((p[3][0]+p[3][1]) + (p[3][2]+p[3][3]));
  sum += __shfl_xor(sum, 16);
  sum += __shfl_xor(sum, 32);
  l = l*alpha + sum;
#pragma unroll
  for (int dc = 0; dc < 4; ++dc)
#pragma unroll
    for (int r = 0; r < 4; ++r) o[dc][r] *= alpha;
  // ---- pack P to bf16 pairs; remap C-layout -> B-frag via shuffles ----
  unsigned pc[4][2];
#pragma unroll
  for (int c = 0; c < 4; ++c){
    pc[c][0] = packbf(p[c][0], p[c][1]);
    pc[c][1] = packbf(p[c][2], p[c][3]);
  }
  const int sA = ((quad & 1)*2)*16 + ln;
  const int sB = sA + 16;
  const bool hi = quad >= 2;
#pragma unroll
  for (int kh = 0; kh < 2; ++kh){
    unsigned a0 = (unsigned)__shfl((int)pc[2*kh][0],   sA);
    unsigned b0 = (unsigned)__shfl((int)pc[2*kh+1][0], sA);
    unsigned a1 = (unsigned)__shfl((int)pc[2*kh][1],   sA);
    unsigned b1 = (unsigned)__shfl((int)pc[2*kh+1][1], sA);
    unsigned a2 = (unsigned)__shfl((int)pc[2*kh][0],   sB);
    unsigned b2 = (unsigned)__shfl((int)pc[2*kh+1][0], sB);
    unsigned a3 = (unsigned)__shfl((int)pc[2*kh][1],   sB);
    unsigned b3 = (unsigned)__shfl((int)pc[2*kh+1][1], sB);
    uint4v u = { hi ? b0 : a0, hi ? b1 : a1, hi ? b2 : a2, hi ? b3 : a3 };
    short8 pfrag = __builtin_bit_cast(short8, u);
#pragma unroll
    for (int dc = 0; dc < 4; ++dc)
      o[dc] = __builtin_amdgcn_mfma_f32_16x16x32_bf16(va[dc][kh], pfrag, o[dc], 0,0,0);
  }
}

__global__ __launch_bounds__(256) void attn_kernel(
    const u16* __restrict__ qp, const u16* __restrict__ kp,
    const u16* __restrict__ vtp, u16* __restrict__ ao){
  int tid = threadIdx.x, w = tid >> 6, lane = tid & 63;
  int quad = lane >> 4, ln = lane & 15;
  int gw = blockIdx.x*4 + w;                   // 8192 waves
  int bh = gw >> 6, qt = gw & 63;
  int h = bh & 15, b = bh >> 4;
  const u16* Q  = qp  + ((size_t)bh*1024 + qt*16)*64;
  const u16* Kp = kp  + (size_t)bh*65536;
  const u16* Vt = vtp + (size_t)bh*65536;
  short8 qf0 = *(const short8*)(Q + ln*64 + quad*8);       // B[n=ln][k=quad*8+j]
  short8 qf1 = *(const short8*)(Q + ln*64 + 32 + quad*8);
  f32x4 o[4] = {};
  float m = -3e38f, l = 0.f;
  short8 k0[4][2], k1[4][2];
#pragma unroll
  for (int c = 0; c < 4; ++c){
    const u16* kr = Kp + (size_t)(c*16 + ln)*64 + quad*8;
    k0[c][0] = *(const short8*)kr;
    k0[c][1] = *(const short8*)(kr + 32);
  }
  for (int kt2 = 0; kt2 < 8; ++kt2){
    attn_tile(Kp, Vt, 2*kt2,   2*kt2+1,                  k0, k1, qf0, qf1, o, m, l, quad, ln);
    attn_tile(Kp, Vt, 2*kt2+1, (kt2==7)? 15 : 2*kt2+2,   k1, k0, qf0, qf1, o, m, l, quad, ln);
  }
  float rl = 1.f / l;
  size_t orow = ((size_t)b*1024 + qt*16 + ln)*1024 + h*64;
#pragma unroll
  for (int dc = 0; dc < 4; ++dc)
#pragma unroll
    for (int r = 0; r < 4; ++r)
      ao[orow + dc*16 + quad*4 + r] = f2bf(o[dc][r] * rl);
}

// ---------------- launch ----------------
// Arena: ada@0 | wqkvt@0.25M | wot@6.25M | w1t@8.25M | w2t@16.25M
//   region A 16MB @24.25M : h -> qp -> h2
//   region B 48MB @40.25M : qkv -> { attnb(16) | xmid(32 f32 @56.25M) }
//   region C 32MB @88.25M : kp+vt -> hid(chunked)
//   hidF 64MB @120.25M (only if ws_size >= 184.25 MiB)
extern "C" void kernel_launch(void* const* d_in, const int* in_sizes, int n_in,
                              void* d_out, int out_size, void* d_ws, size_t ws_size,
                              hipStream_t stream){
  const float* x    = (const float*)d_in[0];
  const float* cosT = (const float*)d_in[3];
  const float* sinT = (const float*)d_in[4];
  const float* c    = (const float*)d_in[6];
  const float* ln1w = (const float*)d_in[7];
  const float* Wq   = (const float*)d_in[8];
  const float* Wk   = (const float*)d_in[9];
  const float* Wv   = (const float*)d_in[10];
  const float* Wo   = (const float*)d_in[11];
  const float* ln2w = (const float*)d_in[12];
  const float* W1   = (const float*)d_in[13];
  const float* b1   = (const float*)d_in[14];
  const float* W2   = (const float*)d_in[15];
  const float* b2   = (const float*)d_in[16];
  const float* adaW = (const float*)d_in[17];
  const float* adaB = (const float*)d_in[18];

  char* ws = (char*)d_ws;
  float* ada  = (float*)(ws);
  u16* wqkvt  = (u16*)  (ws + 262144);
  u16* wot    = (u16*)  (ws + 6553600);
  u16* w1t    = (u16*)  (ws + 8650752);
  u16* w2t    = (u16*)  (ws + 17039360);
  u16* h      = (u16*)  (ws + 25427968);
  u16* qp     = (u16*)  (ws + 25427968);
  u16* h2     = (u16*)  (ws + 25427968);
  u16* qkv    = (u16*)  (ws + 42205184);
  u16* attnb  = (u16*)  (ws + 42205184);
  float* xmid = (float*)(ws + 58982400);
  u16* kp     = (u16*)  (ws + 92536832);
  u16* vt     = (u16*)  (ws + 109314048);
  u16* hid    = (u16*)  (ws + 92536832);
  u16* hidF   = (u16*)  (ws + 126091264);
  float* out  = (float*)d_out;
  const bool bigws = ws_size >= (size_t)193200128;

  ada_kernel<<<192, 256, 0, stream>>>(c, adaW, adaB, ada);
  transpose_cast<<<dim3(16,16), 256, 0, stream>>>(Wq, wqkvt,             1024, 1024);
  transpose_cast<<<dim3(16,16), 256, 0, stream>>>(Wk, wqkvt + 1024*1024, 1024, 1024);
  transpose_cast<<<dim3(16,16), 256, 0, stream>>>(Wv, wqkvt + 2048*1024, 1024, 1024);
  transpose_cast<<<dim3(16,16), 256, 0, stream>>>(Wo, wot,               1024, 1024);
  transpose_cast<<<dim3(64,16), 256, 0, stream>>>(W1, w1t,               1024, 4096);
  transpose_cast<<<dim3(16,64), 256, 0, stream>>>(W2, w2t,               4096, 1024);
  ln_mod<<<8192, 256, 0, stream>>>(x, h, ln1w, ada, 0, 1024);
  gemm_bt<0><<<dim3(24,64), 256, 0, stream>>>(h, wqkvt, qkv, 8192, 3072, 1024, 0,
                                              nullptr, nullptr, nullptr);
  rope_pack<<<2048, 256, 0, stream>>>(qkv, cosT, sinT, qp, kp, vt);
  attn_kernel<<<2048, 256, 0, stream>>>(qp, kp, vt, attnb);
  gemm_bt<1><<<dim3(8,64), 256, 0, stream>>>(attnb, wot, xmid, 8192, 1024, 1024, 0,
                                             x, ada, nullptr);
  ln_mod<<<8192, 256, 0, stream>>>(xmid, h2, ln2w, ada, 3072, 4096);
  if (bigws){
    gemm_bt<2><<<dim3(32,64), 256, 0, stream>>>(h2, w1t, hidF, 8192, 4096, 1024, 0,
                                                b1, nullptr, nullptr);
    gemm_bt<3><<<dim3(8,64), 256, 0, stream>>>(hidF, w2t, out, 8192, 1024, 4096, 0,
                                               b2, ada, xmid);
  } else {
    for (int cch = 0; cch < 2; ++cch){
      const size_t mo = (size_t)cch*4096;
      gemm_bt<2><<<dim3(32,32), 256, 0, stream>>>(h2 + mo*1024, w1t, hid,
                                                  4096, 4096, 1024, (int)mo,
                                                  b1, nullptr, nullptr);
      gemm_bt<3><<<dim3(8,32), 256, 0, stream>>>(hid, w2t, out + mo*1024,
                                                 4096, 1024, 4096, (int)mo,
                                                 b2, ada, xmid + mo*1024);
    }
  }
}

// Round 5
// 768.784 us; speedup vs baseline: 1.3249x; 1.1932x over previous
//
#include <hip/hip_runtime.h>

typedef unsigned short u16;
typedef __attribute__((ext_vector_type(8))) short short8;
typedef __attribute__((ext_vector_type(4))) float f32x4;
typedef __attribute__((ext_vector_type(4))) unsigned uint4v;

__device__ __forceinline__ float bf2f(u16 u){
  unsigned v = ((unsigned)u) << 16;
  return __builtin_bit_cast(float, v);
}
__device__ __forceinline__ u16 f2bf(float f){
  unsigned u = __builtin_bit_cast(unsigned, f);
  u += 0x7fff + ((u >> 16) & 1);   // RNE
  return (u16)(u >> 16);
}
__device__ __forceinline__ unsigned packbf(float lo, float hi){
  return ((unsigned)f2bf(hi) << 16) | (unsigned)f2bf(lo);
}
__device__ __forceinline__ void async16(const void* g, void* l){
  __builtin_amdgcn_global_load_lds((const __attribute__((address_space(1))) void*)g,
                                   (__attribute__((address_space(3))) void*)l, 16, 0, 0);
}

// ---------------- ada = c @ ada_w + ada_b   [8, 6144] ----------------
__global__ __launch_bounds__(256) void ada_kernel(
    const float* __restrict__ c, const float* __restrict__ aw,
    const float* __restrict__ ab, float* __restrict__ ada){
  int idx = blockIdx.x*256 + threadIdx.x;
  int b = idx / 6144, n = idx % 6144;
  float acc = ab[n];
  const float* cr = c + b*1024;
  for (int k = 0; k < 1024; ++k)
    acc += cr[k] * aw[(size_t)k*6144 + n];
  ada[idx] = acc;
}

// ---------------- transpose + cast f32[K][N] -> bf16[N][K] ----------------
__global__ __launch_bounds__(256) void transpose_cast(
    const float* __restrict__ src, u16* __restrict__ dst, int K, int N){
  __shared__ float t[64][65];
  int n0 = blockIdx.x*64, k0 = blockIdx.y*64;
  int tid = threadIdx.x;
  int cc = tid & 63, r4 = tid >> 6;
#pragma unroll 4
  for (int it = 0; it < 16; ++it){
    int r = it*4 + r4;
    t[r][cc] = src[(size_t)(k0 + r)*N + n0 + cc];
  }
  __syncthreads();
#pragma unroll 4
  for (int it = 0; it < 16; ++it){
    int r = it*4 + r4;
    dst[(size_t)(n0 + r)*K + k0 + cc] = f2bf(t[cc][r]);
  }
}

// ---------------- LayerNorm + adaLN modulate -> bf16 ----------------
__global__ __launch_bounds__(256) void ln_mod(
    const float* __restrict__ x, u16* __restrict__ out,
    const float* __restrict__ w, const float* __restrict__ ada,
    int shift_off, int scale_off){
  int t = blockIdx.x, tid = threadIdx.x;
  const float* xr = x + (size_t)t*1024;
  float v[4]; float s = 0.f, ss = 0.f;
#pragma unroll
  for (int i = 0; i < 4; ++i){ v[i] = xr[tid + i*256]; s += v[i]; ss += v[i]*v[i]; }
  for (int d = 1; d < 64; d <<= 1){ s += __shfl_xor(s, d); ss += __shfl_xor(ss, d); }
  __shared__ float red[8];
  int wv = tid >> 6;
  if ((tid & 63) == 0){ red[wv] = s; red[4+wv] = ss; }
  __syncthreads();
  s = red[0]+red[1]+red[2]+red[3];
  ss = red[4]+red[5]+red[6]+red[7];
  float mu = s * (1.f/1024.f);
  float var = ss * (1.f/1024.f) - mu*mu;
  float rs = rsqrtf(var + 1e-5f);
  int b = t >> 10;
  const float* sh = ada + b*6144 + shift_off;
  const float* sc = ada + b*6144 + scale_off;
#pragma unroll
  for (int i = 0; i < 4; ++i){
    int cidx = tid + i*256;
    float hh = (v[i]-mu)*rs*w[cidx]*(1.f + sc[cidx]) + sh[cidx];
    out[(size_t)t*1024 + cidx] = f2bf(hh);
  }
}

// ---------------- GEMM: A[M][K] bf16 @ Bt[N][K]^T, 128x128 tile ----------------
template<int EPI>
__global__ __launch_bounds__(256) void gemm_bt(
    const u16* __restrict__ A, const u16* __restrict__ Bt,
    void* __restrict__ Cout, int M, int N, int K, int m_off,
    const float* __restrict__ e0, const float* __restrict__ e1,
    const float* __restrict__ e2){
  __shared__ u16 As[128*32];
  __shared__ u16 Bs[128*32];
  const int tid = threadIdx.x;
  const int n0 = blockIdx.x*128, m0 = blockIdx.y*128;
  const int w = tid >> 6, lane = tid & 63, quad = lane >> 4, ln = lane & 15;
  const int wm = (w >> 1)*64, wn = (w & 1)*64;
  f32x4 acc[4][4] = {};
  const u16* ga = A  + (size_t)(m0 + (tid>>2))*K + (tid&3)*8;
  const u16* gb = Bt + (size_t)(n0 + (tid>>2))*K + (tid&3)*8;
  u16* lA = As + (tid & 192)*8;
  u16* lB = Bs + (tid & 192)*8;
  const size_t rstep = (size_t)64*K;
  for (int k0 = 0; k0 < K; k0 += 32){
    async16(ga,         lA);
    async16(ga + rstep, lA + 2048);
    async16(gb,         lB);
    async16(gb + rstep, lB + 2048);
    ga += 32; gb += 32;
    __syncthreads();
    short8 af[4], bfr[4];
#pragma unroll
    for (int i = 0; i < 4; ++i){
      af[i]  = *(const short8*)(As + (wm + i*16 + ln)*32 + quad*8);
      bfr[i] = *(const short8*)(Bs + (wn + i*16 + ln)*32 + quad*8);
    }
#pragma unroll
    for (int i = 0; i < 4; ++i)
#pragma unroll
      for (int j = 0; j < 4; ++j)
        acc[i][j] = __builtin_amdgcn_mfma_f32_16x16x32_bf16(af[i], bfr[j], acc[i][j], 0, 0, 0);
    __syncthreads();
  }
  const int mB = m0 + wm + quad*4;
  const int nB = n0 + wn + ln;
#pragma unroll
  for (int i = 0; i < 4; ++i){
#pragma unroll
    for (int r = 0; r < 4; ++r){
      const int m = mB + i*16 + r;
#pragma unroll
      for (int j = 0; j < 4; ++j){
        const int n = nB + j*16;
        float v = acc[i][j][r];
        if (EPI == 0){
          ((u16*)Cout)[(size_t)m*N + n] = f2bf(v);
        } else if (EPI == 1){
          const int b = (m + m_off) >> 10;
          float g = e1[b*6144 + 2048 + n];
          ((float*)Cout)[(size_t)m*N + n] = e0[(size_t)m*N + n] + g*v;
        } else if (EPI == 2){
          float xx = v + e0[n];
          float th = tanhf(0.7978845608f*(xx + 0.044715f*xx*xx*xx));
          ((u16*)Cout)[(size_t)m*N + n] = f2bf(0.5f*xx*(1.0f + th));
        } else {
          const int b = (m + m_off) >> 10;
          float g = e1[b*6144 + 5120 + n];
          ((float*)Cout)[(size_t)m*N + n] = e2[(size_t)m*N + n] + g*(v + e0[n]);
        }
      }
    }
  }
}

// ---------------- RoPE + repack; q pre-scaled by 1/sqrt(D)=0.125 ----------------
// qp: [bh][l][64]  (B-frag friendly)
// kp: [bh][kt=16][dhalf=2][key=64][32]   (8KB tiles, async16-contiguous)
// vt: [bh][kt=16][khalf=2][d=64][key=32] (8KB tiles)
__global__ __launch_bounds__(256) void rope_pack(
    const u16* __restrict__ qkv, const float* __restrict__ cosT,
    const float* __restrict__ sinT, u16* __restrict__ qp,
    u16* __restrict__ kp, u16* __restrict__ vt){
  int blk = blockIdx.x;                       // B*H*(L/64) = 2048
  int lt = blk & 15, h = (blk >> 4) & 15, b = blk >> 8;
  int l0 = lt*64;
  int bh = b*16 + h;
  __shared__ u16 vl[64][68];
  int tid = threadIdx.x;
  size_t tile_base = (size_t)bh*65536 + (size_t)lt*4096;
#pragma unroll 4
  for (int it = 0; it < 16; ++it){
    int idx = it*256 + tid;
    int r = idx >> 6, d = idx & 63;
    int t = b*1024 + l0 + r;
    int pos = l0 + r;
    const u16* row = qkv + (size_t)t*3072 + h*64;
    float qv = bf2f(row[d]), kv = bf2f(row[1024+d]);
    float qo, ko;
    if (d < 32){
      float cs = cosT[pos*32 + d], sn = sinT[pos*32 + d];
      qo = qv*cs - bf2f(row[d+32])*sn;
      ko = kv*cs - bf2f(row[1024+d+32])*sn;
    } else {
      int dd = d - 32;
      float cs = cosT[pos*32 + dd], sn = sinT[pos*32 + dd];
      qo = qv*cs + bf2f(row[d-32])*sn;
      ko = kv*cs + bf2f(row[1024+d-32])*sn;
    }
    qp[((size_t)bh*1024 + l0 + r)*64 + d] = f2bf(qo*0.125f);
    kp[tile_base + (d>>5)*2048 + r*32 + (d&31)] = f2bf(ko);
    vl[d][r] = row[2048 + d];
  }
  __syncthreads();
#pragma unroll 4
  for (int it = 0; it < 16; ++it){
    int idx = it*256 + tid;
    int d = idx >> 6, cc = idx & 63;
    vt[tile_base + (cc>>5)*2048 + d*32 + (cc&31)] = vl[d][cc];
  }
}

// ---------------- flash attention v3b: LDS-shared K/V, S^T layout ----------------
// block = one (b,h) x 64 q-rows (4 waves x 16). Per 64-key tile: stage K(8KB)+V(8KB)
// into LDS via async16 (per-lane global addr = base + lane*16B; LDS base wave-uniform).
// S^T = K·Q^T; per-lane scalar m/l (qrow = ln); PV via shuffle-remapped P^T.
__global__ __launch_bounds__(256) void attn_kernel(
    const u16* __restrict__ qp, const u16* __restrict__ kp,
    const u16* __restrict__ vtp, u16* __restrict__ ao){
  __shared__ u16 Kb[4096];   // [dhalf][key64][32]
  __shared__ u16 Vb[4096];   // [khalf][d64][key32]
  int tid = threadIdx.x, w = tid >> 6, lane = tid & 63;
  int quad = lane >> 4, ln = lane & 15;
  int bh = blockIdx.x >> 4, qb = blockIdx.x & 15;   // 2048 blocks
  int h = bh & 15, b = bh >> 4;
  const u16* Q  = qp  + ((size_t)bh*1024 + qb*64 + w*16)*64;
  const u16* Kg = kp  + (size_t)bh*65536;
  const u16* Vg = vtp + (size_t)bh*65536;
  short8 qf0 = *(const short8*)(Q + ln*64 + quad*8);       // B[n=ln][k=quad*8+j]
  short8 qf1 = *(const short8*)(Q + ln*64 + 32 + quad*8);
  f32x4 o[4] = {};
  float m = -3e38f, l = 0.f;
  for (int kt = 0; kt < 16; ++kt){
    // per-lane global source: tile base + segment + lane*16B (8 u16)
    const u16* ktg = Kg + kt*4096 + lane*8;
    const u16* vtg = Vg + kt*4096 + lane*8;
    async16(ktg + (w*2+0)*512, Kb + (w*2+0)*512);
    async16(ktg + (w*2+1)*512, Kb + (w*2+1)*512);
    async16(vtg + (w*2+0)*512, Vb + (w*2+0)*512);
    async16(vtg + (w*2+1)*512, Vb + (w*2+1)*512);
    __syncthreads();
    // ---- S^T = K·Q^T ----
    f32x4 zz = {0.f, 0.f, 0.f, 0.f};
    f32x4 st[4];
#pragma unroll
    for (int c = 0; c < 4; ++c){
      short8 k0 = *(const short8*)(Kb +        (c*16 + ln)*32 + quad*8);
      short8 k1 = *(const short8*)(Kb + 2048 + (c*16 + ln)*32 + quad*8);
      st[c] = __builtin_amdgcn_mfma_f32_16x16x32_bf16(k0, qf0, zz, 0,0,0);
      st[c] = __builtin_amdgcn_mfma_f32_16x16x32_bf16(k1, qf1, st[c], 0,0,0);
    }
    // V frags (LDS; needed after softmax)
    short8 va[4][2];
#pragma unroll
    for (int dc = 0; dc < 4; ++dc)
#pragma unroll
      for (int kh = 0; kh < 2; ++kh)
        va[dc][kh] = *(const short8*)(Vb + kh*2048 + (dc*16 + ln)*32 + quad*8);
    // ---- softmax (per-lane: qrow = ln) ----
    float mx = st[0][0];
#pragma unroll
    for (int c = 0; c < 4; ++c)
#pragma unroll
      for (int r = 0; r < 4; ++r) mx = fmaxf(mx, st[c][r]);
    mx = fmaxf(mx, __shfl_xor(mx, 16));
    mx = fmaxf(mx, __shfl_xor(mx, 32));
    float mn = fmaxf(m, mx);
    float alpha = __expf(m - mn);
    m = mn;
    float p[4][4];
#pragma unroll
    for (int c = 0; c < 4; ++c)
#pragma unroll
      for (int r = 0; r < 4; ++r) p[c][r] = __expf(st[c][r] - mn);
    float sum = ((p[0][0]+p[0][1]) + (p[0][2]+p[0][3])) + ((p[1][0]+p[1][1]) + (p[1][2]+p[1][3]))
              + ((p[2][0]+p[2][1]) + (p[2][2]+p[2][3])) + ((p[3][0]+p[3][1]) + (p[3][2]+p[3][3]));
    sum += __shfl_xor(sum, 16);
    sum += __shfl_xor(sum, 32);
    l = l*alpha + sum;
#pragma unroll
    for (int dc = 0; dc < 4; ++dc)
#pragma unroll
      for (int r = 0; r < 4; ++r) o[dc][r] *= alpha;
    // ---- pack P to bf16; remap C-layout -> B-frag via one-stage shuffles ----
    unsigned pc[4][2];
#pragma unroll
    for (int c = 0; c < 4; ++c){
      pc[c][0] = packbf(p[c][0], p[c][1]);
      pc[c][1] = packbf(p[c][2], p[c][3]);
    }
    const int sA = ((quad & 1)*2)*16 + ln;
    const int sB = sA + 16;
    const bool hi = quad >= 2;
#pragma unroll
    for (int kh = 0; kh < 2; ++kh){
      unsigned a0 = (unsigned)__shfl((int)pc[2*kh][0],   sA);
      unsigned b0 = (unsigned)__shfl((int)pc[2*kh+1][0], sA);
      unsigned a1 = (unsigned)__shfl((int)pc[2*kh][1],   sA);
      unsigned b1 = (unsigned)__shfl((int)pc[2*kh+1][1], sA);
      unsigned a2 = (unsigned)__shfl((int)pc[2*kh][0],   sB);
      unsigned b2 = (unsigned)__shfl((int)pc[2*kh+1][0], sB);
      unsigned a3 = (unsigned)__shfl((int)pc[2*kh][1],   sB);
      unsigned b3 = (unsigned)__shfl((int)pc[2*kh+1][1], sB);
      uint4v u = { hi ? b0 : a0, hi ? b1 : a1, hi ? b2 : a2, hi ? b3 : a3 };
      short8 pfrag = __builtin_bit_cast(short8, u);
#pragma unroll
      for (int dc = 0; dc < 4; ++dc)
        o[dc] = __builtin_amdgcn_mfma_f32_16x16x32_bf16(va[dc][kh], pfrag, o[dc], 0,0,0);
    }
    __syncthreads();
  }
  float rl = 1.f / l;
  size_t orow = ((size_t)b*1024 + qb*64 + w*16 + ln)*1024 + h*64;
#pragma unroll
  for (int dc = 0; dc < 4; ++dc)
#pragma unroll
    for (int r = 0; r < 4; ++r)
      ao[orow + dc*16 + quad*4 + r] = f2bf(o[dc][r] * rl);
}

// ---------------- launch ----------------
// Arena: ada@0 | wqkvt@0.25M | wot@6.25M | w1t@8.25M | w2t@16.25M
//   region A 16MB @24.25M : h -> qp -> h2
//   region B 48MB @40.25M : qkv -> { attnb(16) | xmid(32 f32 @56.25M) }
//   region C 32MB @88.25M : kp+vt -> hid(chunked)
//   hidF 64MB @120.25M (only if ws_size >= 184.25 MiB)
extern "C" void kernel_launch(void* const* d_in, const int* in_sizes, int n_in,
                              void* d_out, int out_size, void* d_ws, size_t ws_size,
                              hipStream_t stream){
  const float* x    = (const float*)d_in[0];
  const float* cosT = (const float*)d_in[3];
  const float* sinT = (const float*)d_in[4];
  const float* c    = (const float*)d_in[6];
  const float* ln1w = (const float*)d_in[7];
  const float* Wq   = (const float*)d_in[8];
  const float* Wk   = (const float*)d_in[9];
  const float* Wv   = (const float*)d_in[10];
  const float* Wo   = (const float*)d_in[11];
  const float* ln2w = (const float*)d_in[12];
  const float* W1   = (const float*)d_in[13];
  const float* b1   = (const float*)d_in[14];
  const float* W2   = (const float*)d_in[15];
  const float* b2   = (const float*)d_in[16];
  const float* adaW = (const float*)d_in[17];
  const float* adaB = (const float*)d_in[18];

  char* ws = (char*)d_ws;
  float* ada  = (float*)(ws);
  u16* wqkvt  = (u16*)  (ws + 262144);
  u16* wot    = (u16*)  (ws + 6553600);
  u16* w1t    = (u16*)  (ws + 8650752);
  u16* w2t    = (u16*)  (ws + 17039360);
  u16* h      = (u16*)  (ws + 25427968);
  u16* qp     = (u16*)  (ws + 25427968);
  u16* h2     = (u16*)  (ws + 25427968);
  u16* qkv    = (u16*)  (ws + 42205184);
  u16* attnb  = (u16*)  (ws + 42205184);
  float* xmid = (float*)(ws + 58982400);
  u16* kp     = (u16*)  (ws + 92536832);
  u16* vt     = (u16*)  (ws + 109314048);
  u16* hid    = (u16*)  (ws + 92536832);
  u16* hidF   = (u16*)  (ws + 126091264);
  float* out  = (float*)d_out;
  const bool bigws = ws_size >= (size_t)193200128;

  ada_kernel<<<192, 256, 0, stream>>>(c, adaW, adaB, ada);
  transpose_cast<<<dim3(16,16), 256, 0, stream>>>(Wq, wqkvt,             1024, 1024);
  transpose_cast<<<dim3(16,16), 256, 0, stream>>>(Wk, wqkvt + 1024*1024, 1024, 1024);
  transpose_cast<<<dim3(16,16), 256, 0, stream>>>(Wv, wqkvt + 2048*1024, 1024, 1024);
  transpose_cast<<<dim3(16,16), 256, 0, stream>>>(Wo, wot,               1024, 1024);
  transpose_cast<<<dim3(64,16), 256, 0, stream>>>(W1, w1t,               1024, 4096);
  transpose_cast<<<dim3(16,64), 256, 0, stream>>>(W2, w2t,               4096, 1024);
  ln_mod<<<8192, 256, 0, stream>>>(x, h, ln1w, ada, 0, 1024);
  gemm_bt<0><<<dim3(24,64), 256, 0, stream>>>(h, wqkvt, qkv, 8192, 3072, 1024, 0,
                                              nullptr, nullptr, nullptr);
  rope_pack<<<2048, 256, 0, stream>>>(qkv, cosT, sinT, qp, kp, vt);
  attn_kernel<<<2048, 256, 0, stream>>>(qp, kp, vt, attnb);
  gemm_bt<1><<<dim3(8,64), 256, 0, stream>>>(attnb, wot, xmid, 8192, 1024, 1024, 0,
                                             x, ada, nullptr);
  ln_mod<<<8192, 256, 0, stream>>>(xmid, h2, ln2w, ada, 3072, 4096);
  if (bigws){
    gemm_bt<2><<<dim3(32,64), 256, 0, stream>>>(h2, w1t, hidF, 8192, 4096, 1024, 0,
                                                b1, nullptr, nullptr);
    gemm_bt<3><<<dim3(8,64), 256, 0, stream>>>(hidF, w2t, out, 8192, 1024, 4096, 0,
                                               b2, ada, xmid);
  } else {
    for (int cch = 0; cch < 2; ++cch){
      const size_t mo = (size_t)cch*4096;
      gemm_bt<2><<<dim3(32,32), 256, 0, stream>>>(h2 + mo*1024, w1t, hid,
                                                  4096, 4096, 1024, (int)mo,
                                                  b1, nullptr, nullptr);
      gemm_bt<3><<<dim3(8,32), 256, 0, stream>>>(hid, w2t, out + mo*1024,
                                                 4096, 1024, 4096, (int)mo,
                                                 b2, ada, xmid + mo*1024);
    }
  }
}

// Round 6
// 661.900 us; speedup vs baseline: 1.5388x; 1.1615x over previous
//
#include <hip/hip_runtime.h>

typedef unsigned short u16;
typedef __attribute__((ext_vector_type(8))) short short8;
typedef __attribute__((ext_vector_type(4))) float f32x4;
typedef __attribute__((ext_vector_type(4))) unsigned uint4v;

__device__ __forceinline__ float bf2f(u16 u){
  unsigned v = ((unsigned)u) << 16;
  return __builtin_bit_cast(float, v);
}
__device__ __forceinline__ u16 f2bf(float f){
  unsigned u = __builtin_bit_cast(unsigned, f);
  u += 0x7fff + ((u >> 16) & 1);   // RNE
  return (u16)(u >> 16);
}
__device__ __forceinline__ unsigned packbf(float lo, float hi){
  return ((unsigned)f2bf(hi) << 16) | (unsigned)f2bf(lo);
}
__device__ __forceinline__ void async16(const void* g, void* l){
  __builtin_amdgcn_global_load_lds((const __attribute__((address_space(1))) void*)g,
                                   (__attribute__((address_space(3))) void*)l, 16, 0, 0);
}

// ---------------- ada partials: part[kc][b][n] = sum_{k in chunk} c[b,k]*aw[k,n] ----
__global__ __launch_bounds__(256) void ada_partial(
    const float* __restrict__ c, const float* __restrict__ aw,
    float* __restrict__ part){
  int n  = blockIdx.x*256 + threadIdx.x;    // 24 x-blocks
  int b  = blockIdx.y;                      // 8
  int kc = blockIdx.z;                      // 8
  const float* cr  = c + b*1024 + kc*128;
  const float* awp = aw + (size_t)(kc*128)*6144 + n;
  float acc = 0.f;
#pragma unroll 8
  for (int k = 0; k < 128; ++k)
    acc += cr[k] * awp[(size_t)k*6144];
  part[(size_t)(kc*8 + b)*6144 + n] = acc;
}

// ---------------- ada = sum_kc part + ab ----------------
__global__ __launch_bounds__(256) void ada_reduce(
    const float* __restrict__ part, const float* __restrict__ ab,
    float* __restrict__ ada){
  int idx = blockIdx.x*256 + threadIdx.x;   // 192 blocks
  int n = idx % 6144;
  float acc = ab[n];
#pragma unroll
  for (int kc = 0; kc < 8; ++kc)
    acc += part[(size_t)kc*49152 + idx];
  ada[idx] = acc;
}

// ---------------- transpose + cast f32[K][N] -> bf16[N][K] ----------------
__global__ __launch_bounds__(256) void transpose_cast(
    const float* __restrict__ src, u16* __restrict__ dst, int K, int N){
  __shared__ float t[64][65];
  int n0 = blockIdx.x*64, k0 = blockIdx.y*64;
  int tid = threadIdx.x;
  int cc = tid & 63, r4 = tid >> 6;
#pragma unroll 4
  for (int it = 0; it < 16; ++it){
    int r = it*4 + r4;
    t[r][cc] = src[(size_t)(k0 + r)*N + n0 + cc];
  }
  __syncthreads();
#pragma unroll 4
  for (int it = 0; it < 16; ++it){
    int r = it*4 + r4;
    dst[(size_t)(n0 + r)*K + k0 + cc] = f2bf(t[cc][r]);
  }
}

// ---------------- LayerNorm + adaLN modulate -> bf16 ----------------
__global__ __launch_bounds__(256) void ln_mod(
    const float* __restrict__ x, u16* __restrict__ out,
    const float* __restrict__ w, const float* __restrict__ ada,
    int shift_off, int scale_off){
  int t = blockIdx.x, tid = threadIdx.x;
  const float* xr = x + (size_t)t*1024;
  float v[4]; float s = 0.f, ss = 0.f;
#pragma unroll
  for (int i = 0; i < 4; ++i){ v[i] = xr[tid + i*256]; s += v[i]; ss += v[i]*v[i]; }
  for (int d = 1; d < 64; d <<= 1){ s += __shfl_xor(s, d); ss += __shfl_xor(ss, d); }
  __shared__ float red[8];
  int wv = tid >> 6;
  if ((tid & 63) == 0){ red[wv] = s; red[4+wv] = ss; }
  __syncthreads();
  s = red[0]+red[1]+red[2]+red[3];
  ss = red[4]+red[5]+red[6]+red[7];
  float mu = s * (1.f/1024.f);
  float var = ss * (1.f/1024.f) - mu*mu;
  float rs = rsqrtf(var + 1e-5f);
  int b = t >> 10;
  const float* sh = ada + b*6144 + shift_off;
  const float* sc = ada + b*6144 + scale_off;
#pragma unroll
  for (int i = 0; i < 4; ++i){
    int cidx = tid + i*256;
    float hh = (v[i]-mu)*rs*w[cidx]*(1.f + sc[cidx]) + sh[cidx];
    out[(size_t)t*1024 + cidx] = f2bf(hh);
  }
}

// ---------------- GEMM: A[M][K] bf16 @ Bt[N][K]^T, 128x128 tile ----------------
template<int EPI>
__global__ __launch_bounds__(256) void gemm_bt(
    const u16* __restrict__ A, const u16* __restrict__ Bt,
    void* __restrict__ Cout, int M, int N, int K, int m_off,
    const float* __restrict__ e0, const float* __restrict__ e1,
    const float* __restrict__ e2){
  __shared__ u16 As[128*32];
  __shared__ u16 Bs[128*32];
  const int tid = threadIdx.x;
  const int n0 = blockIdx.x*128, m0 = blockIdx.y*128;
  const int w = tid >> 6, lane = tid & 63, quad = lane >> 4, ln = lane & 15;
  const int wm = (w >> 1)*64, wn = (w & 1)*64;
  f32x4 acc[4][4] = {};
  const u16* ga = A  + (size_t)(m0 + (tid>>2))*K + (tid&3)*8;
  const u16* gb = Bt + (size_t)(n0 + (tid>>2))*K + (tid&3)*8;
  u16* lA = As + (tid & 192)*8;
  u16* lB = Bs + (tid & 192)*8;
  const size_t rstep = (size_t)64*K;
  for (int k0 = 0; k0 < K; k0 += 32){
    async16(ga,         lA);
    async16(ga + rstep, lA + 2048);
    async16(gb,         lB);
    async16(gb + rstep, lB + 2048);
    ga += 32; gb += 32;
    __syncthreads();
    short8 af[4], bfr[4];
#pragma unroll
    for (int i = 0; i < 4; ++i){
      af[i]  = *(const short8*)(As + (wm + i*16 + ln)*32 + quad*8);
      bfr[i] = *(const short8*)(Bs + (wn + i*16 + ln)*32 + quad*8);
    }
#pragma unroll
    for (int i = 0; i < 4; ++i)
#pragma unroll
      for (int j = 0; j < 4; ++j)
        acc[i][j] = __builtin_amdgcn_mfma_f32_16x16x32_bf16(af[i], bfr[j], acc[i][j], 0, 0, 0);
    __syncthreads();
  }
  const int mB = m0 + wm + quad*4;
  const int nB = n0 + wn + ln;
#pragma unroll
  for (int i = 0; i < 4; ++i){
#pragma unroll
    for (int r = 0; r < 4; ++r){
      const int m = mB + i*16 + r;
#pragma unroll
      for (int j = 0; j < 4; ++j){
        const int n = nB + j*16;
        float v = acc[i][j][r];
        if (EPI == 0){
          ((u16*)Cout)[(size_t)m*N + n] = f2bf(v);
        } else if (EPI == 1){
          const int b = (m + m_off) >> 10;
          float g = e1[b*6144 + 2048 + n];
          ((float*)Cout)[(size_t)m*N + n] = e0[(size_t)m*N + n] + g*v;
        } else if (EPI == 2){
          float xx = v + e0[n];
          float th = tanhf(0.7978845608f*(xx + 0.044715f*xx*xx*xx));
          ((u16*)Cout)[(size_t)m*N + n] = f2bf(0.5f*xx*(1.0f + th));
        } else {
          const int b = (m + m_off) >> 10;
          float g = e1[b*6144 + 5120 + n];
          ((float*)Cout)[(size_t)m*N + n] = e2[(size_t)m*N + n] + g*(v + e0[n]);
        }
      }
    }
  }
}

// ---------------- RoPE + repack; q pre-scaled by 1/sqrt(D)=0.125 ----------------
// qp: [bh][l][64]  (B-frag friendly)
// kp: [bh][kt=16][dhalf=2][key=64][32]   (8KB tiles, async16-contiguous)
// vt: [bh][kt=16][khalf=2][d=64][key=32] (8KB tiles)
__global__ __launch_bounds__(256) void rope_pack(
    const u16* __restrict__ qkv, const float* __restrict__ cosT,
    const float* __restrict__ sinT, u16* __restrict__ qp,
    u16* __restrict__ kp, u16* __restrict__ vt){
  int blk = blockIdx.x;                       // B*H*(L/64) = 2048
  int lt = blk & 15, h = (blk >> 4) & 15, b = blk >> 8;
  int l0 = lt*64;
  int bh = b*16 + h;
  __shared__ u16 vl[64][68];
  int tid = threadIdx.x;
  size_t tile_base = (size_t)bh*65536 + (size_t)lt*4096;
#pragma unroll 4
  for (int it = 0; it < 16; ++it){
    int idx = it*256 + tid;
    int r = idx >> 6, d = idx & 63;
    int t = b*1024 + l0 + r;
    int pos = l0 + r;
    const u16* row = qkv + (size_t)t*3072 + h*64;
    float qv = bf2f(row[d]), kv = bf2f(row[1024+d]);
    float qo, ko;
    if (d < 32){
      float cs = cosT[pos*32 + d], sn = sinT[pos*32 + d];
      qo = qv*cs - bf2f(row[d+32])*sn;
      ko = kv*cs - bf2f(row[1024+d+32])*sn;
    } else {
      int dd = d - 32;
      float cs = cosT[pos*32 + dd], sn = sinT[pos*32 + dd];
      qo = qv*cs + bf2f(row[d-32])*sn;
      ko = kv*cs + bf2f(row[1024+d-32])*sn;
    }
    qp[((size_t)bh*1024 + l0 + r)*64 + d] = f2bf(qo*0.125f);
    kp[tile_base + (d>>5)*2048 + r*32 + (d&31)] = f2bf(ko);
    vl[d][r] = row[2048 + d];
  }
  __syncthreads();
#pragma unroll 4
  for (int it = 0; it < 16; ++it){
    int idx = it*256 + tid;
    int d = idx >> 6, cc = idx & 63;
    vt[tile_base + (cc>>5)*2048 + d*32 + (cc&31)] = vl[d][cc];
  }
}

// ---------------- flash attention v3b: LDS-shared K/V, S^T layout ----------------
__global__ __launch_bounds__(256) void attn_kernel(
    const u16* __restrict__ qp, const u16* __restrict__ kp,
    const u16* __restrict__ vtp, u16* __restrict__ ao){
  __shared__ u16 Kb[4096];   // [dhalf][key64][32]
  __shared__ u16 Vb[4096];   // [khalf][d64][key32]
  int tid = threadIdx.x, w = tid >> 6, lane = tid & 63;
  int quad = lane >> 4, ln = lane & 15;
  int bh = blockIdx.x >> 4, qb = blockIdx.x & 15;   // 2048 blocks
  int h = bh & 15, b = bh >> 4;
  const u16* Q  = qp  + ((size_t)bh*1024 + qb*64 + w*16)*64;
  const u16* Kg = kp  + (size_t)bh*65536;
  const u16* Vg = vtp + (size_t)bh*65536;
  short8 qf0 = *(const short8*)(Q + ln*64 + quad*8);       // B[n=ln][k=quad*8+j]
  short8 qf1 = *(const short8*)(Q + ln*64 + 32 + quad*8);
  f32x4 o[4] = {};
  float m = -3e38f, l = 0.f;
  for (int kt = 0; kt < 16; ++kt){
    const u16* ktg = Kg + kt*4096 + lane*8;
    const u16* vtg = Vg + kt*4096 + lane*8;
    async16(ktg + (w*2+0)*512, Kb + (w*2+0)*512);
    async16(ktg + (w*2+1)*512, Kb + (w*2+1)*512);
    async16(vtg + (w*2+0)*512, Vb + (w*2+0)*512);
    async16(vtg + (w*2+1)*512, Vb + (w*2+1)*512);
    __syncthreads();
    // ---- S^T = K·Q^T ----
    f32x4 zz = {0.f, 0.f, 0.f, 0.f};
    f32x4 st[4];
#pragma unroll
    for (int c = 0; c < 4; ++c){
      short8 k0 = *(const short8*)(Kb +        (c*16 + ln)*32 + quad*8);
      short8 k1 = *(const short8*)(Kb + 2048 + (c*16 + ln)*32 + quad*8);
      st[c] = __builtin_amdgcn_mfma_f32_16x16x32_bf16(k0, qf0, zz, 0,0,0);
      st[c] = __builtin_amdgcn_mfma_f32_16x16x32_bf16(k1, qf1, st[c], 0,0,0);
    }
    short8 va[4][2];
#pragma unroll
    for (int dc = 0; dc < 4; ++dc)
#pragma unroll
      for (int kh = 0; kh < 2; ++kh)
        va[dc][kh] = *(const short8*)(Vb + kh*2048 + (dc*16 + ln)*32 + quad*8);
    // ---- softmax (per-lane: qrow = ln) ----
    float mx = st[0][0];
#pragma unroll
    for (int c = 0; c < 4; ++c)
#pragma unroll
      for (int r = 0; r < 4; ++r) mx = fmaxf(mx, st[c][r]);
    mx = fmaxf(mx, __shfl_xor(mx, 16));
    mx = fmaxf(mx, __shfl_xor(mx, 32));
    float mn = fmaxf(m, mx);
    float alpha = __expf(m - mn);
    m = mn;
    float p[4][4];
#pragma unroll
    for (int c = 0; c < 4; ++c)
#pragma unroll
      for (int r = 0; r < 4; ++r) p[c][r] = __expf(st[c][r] - mn);
    float sum = ((p[0][0]+p[0][1]) + (p[0][2]+p[0][3])) + ((p[1][0]+p[1][1]) + (p[1][2]+p[1][3]))
              + ((p[2][0]+p[2][1]) + (p[2][2]+p[2][3])) + ((p[3][0]+p[3][1]) + (p[3][2]+p[3][3]));
    sum += __shfl_xor(sum, 16);
    sum += __shfl_xor(sum, 32);
    l = l*alpha + sum;
#pragma unroll
    for (int dc = 0; dc < 4; ++dc)
#pragma unroll
      for (int r = 0; r < 4; ++r) o[dc][r] *= alpha;
    unsigned pc[4][2];
#pragma unroll
    for (int c = 0; c < 4; ++c){
      pc[c][0] = packbf(p[c][0], p[c][1]);
      pc[c][1] = packbf(p[c][2], p[c][3]);
    }
    const int sA = ((quad & 1)*2)*16 + ln;
    const int sB = sA + 16;
    const bool hi = quad >= 2;
#pragma unroll
    for (int kh = 0; kh < 2; ++kh){
      unsigned a0 = (unsigned)__shfl((int)pc[2*kh][0],   sA);
      unsigned b0 = (unsigned)__shfl((int)pc[2*kh+1][0], sA);
      unsigned a1 = (unsigned)__shfl((int)pc[2*kh][1],   sA);
      unsigned b1 = (unsigned)__shfl((int)pc[2*kh+1][1], sA);
      unsigned a2 = (unsigned)__shfl((int)pc[2*kh][0],   sB);
      unsigned b2 = (unsigned)__shfl((int)pc[2*kh+1][0], sB);
      unsigned a3 = (unsigned)__shfl((int)pc[2*kh][1],   sB);
      unsigned b3 = (unsigned)__shfl((int)pc[2*kh+1][1], sB);
      uint4v u = { hi ? b0 : a0, hi ? b1 : a1, hi ? b2 : a2, hi ? b3 : a3 };
      short8 pfrag = __builtin_bit_cast(short8, u);
#pragma unroll
      for (int dc = 0; dc < 4; ++dc)
        o[dc] = __builtin_amdgcn_mfma_f32_16x16x32_bf16(va[dc][kh], pfrag, o[dc], 0,0,0);
    }
    __syncthreads();
  }
  float rl = 1.f / l;
  size_t orow = ((size_t)b*1024 + qb*64 + w*16 + ln)*1024 + h*64;
#pragma unroll
  for (int dc = 0; dc < 4; ++dc)
#pragma unroll
    for (int r = 0; r < 4; ++r)
      ao[orow + dc*16 + quad*4 + r] = f2bf(o[dc][r] * rl);
}

// ---------------- launch ----------------
// Arena: ada@0 | wqkvt@0.25M | wot@6.25M | w1t@8.25M | w2t@16.25M
//   region A 16MB @24.25M : h -> qp -> h2
//   region B 48MB @40.25M : qkv -> { attnb(16) | xmid(32 f32 @56.25M) }
//   region C 32MB @88.25M : ada_part(1.5MB, pre-rope) -> kp+vt -> hid(chunked)
//   hidF 64MB @120.25M (only if ws_size >= 184.25 MiB)
extern "C" void kernel_launch(void* const* d_in, const int* in_sizes, int n_in,
                              void* d_out, int out_size, void* d_ws, size_t ws_size,
                              hipStream_t stream){
  const float* x    = (const float*)d_in[0];
  const float* cosT = (const float*)d_in[3];
  const float* sinT = (const float*)d_in[4];
  const float* c    = (const float*)d_in[6];
  const float* ln1w = (const float*)d_in[7];
  const float* Wq   = (const float*)d_in[8];
  const float* Wk   = (const float*)d_in[9];
  const float* Wv   = (const float*)d_in[10];
  const float* Wo   = (const float*)d_in[11];
  const float* ln2w = (const float*)d_in[12];
  const float* W1   = (const float*)d_in[13];
  const float* b1   = (const float*)d_in[14];
  const float* W2   = (const float*)d_in[15];
  const float* b2   = (const float*)d_in[16];
  const float* adaW = (const float*)d_in[17];
  const float* adaB = (const float*)d_in[18];

  char* ws = (char*)d_ws;
  float* ada  = (float*)(ws);
  u16* wqkvt  = (u16*)  (ws + 262144);
  u16* wot    = (u16*)  (ws + 6553600);
  u16* w1t    = (u16*)  (ws + 8650752);
  u16* w2t    = (u16*)  (ws + 17039360);
  u16* h      = (u16*)  (ws + 25427968);
  u16* qp     = (u16*)  (ws + 25427968);
  u16* h2     = (u16*)  (ws + 25427968);
  u16* qkv    = (u16*)  (ws + 42205184);
  u16* attnb  = (u16*)  (ws + 42205184);
  float* xmid = (float*)(ws + 58982400);
  float* adaP = (float*)(ws + 92536832);   // 1.5 MB, dead before rope_pack
  u16* kp     = (u16*)  (ws + 92536832);
  u16* vt     = (u16*)  (ws + 109314048);
  u16* hid    = (u16*)  (ws + 92536832);
  u16* hidF   = (u16*)  (ws + 126091264);
  float* out  = (float*)d_out;
  const bool bigws = ws_size >= (size_t)193200128;

  ada_partial<<<dim3(24,8,8), 256, 0, stream>>>(c, adaW, adaP);
  ada_reduce<<<192, 256, 0, stream>>>(adaP, adaB, ada);
  transpose_cast<<<dim3(16,16), 256, 0, stream>>>(Wq, wqkvt,             1024, 1024);
  transpose_cast<<<dim3(16,16), 256, 0, stream>>>(Wk, wqkvt + 1024*1024, 1024, 1024);
  transpose_cast<<<dim3(16,16), 256, 0, stream>>>(Wv, wqkvt + 2048*1024, 1024, 1024);
  transpose_cast<<<dim3(16,16), 256, 0, stream>>>(Wo, wot,               1024, 1024);
  transpose_cast<<<dim3(64,16), 256, 0, stream>>>(W1, w1t,               1024, 4096);
  transpose_cast<<<dim3(16,64), 256, 0, stream>>>(W2, w2t,               4096, 1024);
  ln_mod<<<8192, 256, 0, stream>>>(x, h, ln1w, ada, 0, 1024);
  gemm_bt<0><<<dim3(24,64), 256, 0, stream>>>(h, wqkvt, qkv, 8192, 3072, 1024, 0,
                                              nullptr, nullptr, nullptr);
  rope_pack<<<2048, 256, 0, stream>>>(qkv, cosT, sinT, qp, kp, vt);
  attn_kernel<<<2048, 256, 0, stream>>>(qp, kp, vt, attnb);
  gemm_bt<1><<<dim3(8,64), 256, 0, stream>>>(attnb, wot, xmid, 8192, 1024, 1024, 0,
                                             x, ada, nullptr);
  ln_mod<<<8192, 256, 0, stream>>>(xmid, h2, ln2w, ada, 3072, 4096);
  if (bigws){
    gemm_bt<2><<<dim3(32,64), 256, 0, stream>>>(h2, w1t, hidF, 8192, 4096, 1024, 0,
                                                b1, nullptr, nullptr);
    gemm_bt<3><<<dim3(8,64), 256, 0, stream>>>(hidF, w2t, out, 8192, 1024, 4096, 0,
                                               b2, ada, xmid);
  } else {
    for (int cch = 0; cch < 2; ++cch){
      const size_t mo = (size_t)cch*4096;
      gemm_bt<2><<<dim3(32,32), 256, 0, stream>>>(h2 + mo*1024, w1t, hid,
                                                  4096, 4096, 1024, (int)mo,
                                                  b1, nullptr, nullptr);
      gemm_bt<3><<<dim3(8,32), 256, 0, stream>>>(hid, w2t, out + mo*1024,
                                                 4096, 1024, 4096, (int)mo,
                                                 b2, ada, xmid + mo*1024);
    }
  }
}